// Round 10
// baseline (659.761 us; speedup 1.0000x reference)
//
#include <hip/hip_runtime.h>

#define N_NODES 100000
#define N_EDGES 800000
// IN=128, HID=256, OUT=128
#define SCAN_CHUNK 1024
#define SCAN_NB ((N_NODES + SCAN_CHUNK - 1) / SCAN_CHUNK)   // 98

typedef __attribute__((ext_vector_type(8))) short bf16x8;
typedef __attribute__((ext_vector_type(4))) float f32x4;

// ---------------- degree count (int atomics) ----------------
__global__ void count_int_k(const int* __restrict__ dst, int* __restrict__ cnt, int E) {
    int i = blockIdx.x * blockDim.x + threadIdx.x;
    if (i < E) atomicAdd(&cnt[dst[i]], 1);
}

// ---------------- scan pass 1 ----------------
__global__ __launch_bounds__(256) void scan1_k(const int* __restrict__ cnt,
                                               int* __restrict__ offs,
                                               int* __restrict__ bsums, int N) {
    __shared__ int s[256];
    int t = threadIdx.x;
    int base = blockIdx.x * SCAN_CHUNK + t * 4;
    int v0 = (base + 0 < N) ? cnt[base + 0] : 0;
    int v1 = (base + 1 < N) ? cnt[base + 1] : 0;
    int v2 = (base + 2 < N) ? cnt[base + 2] : 0;
    int v3 = (base + 3 < N) ? cnt[base + 3] : 0;
    int tsum = v0 + v1 + v2 + v3;
    s[t] = tsum;
    __syncthreads();
    for (int off = 1; off < 256; off <<= 1) {
        int val = (t >= off) ? s[t - off] : 0;
        __syncthreads();
        s[t] += val;
        __syncthreads();
    }
    int excl = s[t] - tsum;
    if (base + 0 < N) offs[base + 0] = excl;
    if (base + 1 < N) offs[base + 1] = excl + v0;
    if (base + 2 < N) offs[base + 2] = excl + v0 + v1;
    if (base + 3 < N) offs[base + 3] = excl + v0 + v1 + v2;
    if (t == 255) bsums[blockIdx.x] = s[255];
}

// ---------------- scan pass 2 ----------------
__global__ __launch_bounds__(256) void scan2_k(const int* __restrict__ bsums,
                                               int* __restrict__ boffs, int nb) {
    __shared__ int s[256];
    int t = threadIdx.x;
    int v = (t < nb) ? bsums[t] : 0;
    s[t] = v;
    __syncthreads();
    for (int off = 1; off < 256; off <<= 1) {
        int val = (t >= off) ? s[t - off] : 0;
        __syncthreads();
        s[t] += val;
        __syncthreads();
    }
    if (t < nb) boffs[t] = s[t] - v;
}

// ---------------- scan pass 3 ----------------
__global__ void scan3_k(int* __restrict__ offs, int* __restrict__ cursor,
                        const int* __restrict__ boffs, int N, int E) {
    int i = blockIdx.x * blockDim.x + threadIdx.x;
    if (i < N) {
        int v = offs[i] + boffs[i >> 10];
        offs[i] = v;
        cursor[i] = v;
    }
    if (i == 0) offs[N] = E;
}

// ---------------- bucket fill ----------------
__global__ void fill_k(const int* __restrict__ src, const int* __restrict__ dst,
                       int* __restrict__ cursor, int* __restrict__ perm, int E) {
    int e = blockIdx.x * blockDim.x + threadIdx.x;
    if (e < E) {
        int d = dst[e];
        int slot = atomicAdd(&cursor[d], 1);
        perm[slot] = src[e];
    }
}

// ---------------- split fp32 -> (bf16 hi, bf16 lo) ----------------
__device__ inline short2 cvt_split(float a) {
    unsigned u = __builtin_bit_cast(unsigned, a);
    unsigned r = u + 0x7FFF + ((u >> 16) & 1);
    unsigned short h = (unsigned short)(r >> 16);
    float hf = __builtin_bit_cast(float, (unsigned)h << 16);
    float l = a - hf;
    unsigned ul = __builtin_bit_cast(unsigned, l);
    unsigned rl = ul + 0x7FFF + ((ul >> 16) & 1);
    return make_short2((short)h, (short)(rl >> 16));
}

// ---------------- bulk pair-conversion (8 floats/thread) ----------------
__global__ __launch_bounds__(256) void cvt_pair_k(const float* __restrict__ in,
                                                  short* __restrict__ hi,
                                                  short* __restrict__ lo, int n8) {
    int i = blockIdx.x * blockDim.x + threadIdx.x;
    if (i >= n8) return;
    const float4* p = (const float4*)in + (long long)i * 2;
    float4 v0 = p[0], v1 = p[1];
    bf16x8 hv, lv;
    short2 c;
    c = cvt_split(v0.x); hv[0] = c.x; lv[0] = c.y;
    c = cvt_split(v0.y); hv[1] = c.x; lv[1] = c.y;
    c = cvt_split(v0.z); hv[2] = c.x; lv[2] = c.y;
    c = cvt_split(v0.w); hv[3] = c.x; lv[3] = c.y;
    c = cvt_split(v1.x); hv[4] = c.x; lv[4] = c.y;
    c = cvt_split(v1.y); hv[5] = c.x; lv[5] = c.y;
    c = cvt_split(v1.z); hv[6] = c.x; lv[6] = c.y;
    c = cvt_split(v1.w); hv[7] = c.x; lv[7] = c.y;
    *(bf16x8*)&hi[(long long)i * 8] = hv;
    *(bf16x8*)&lo[(long long)i * 8] = lv;
}

// ---------------- gather-mean aggregation -> bf16 hi/lo pair ----------------
__global__ __launch_bounds__(256) void aggmean_k(const float* __restrict__ feat,
                                                 const int* __restrict__ perm,
                                                 const int* __restrict__ offs,
                                                 short* __restrict__ mhi,
                                                 short* __restrict__ mlo, int N) {
    int tid = threadIdx.x;
    int node = blockIdx.x * 2 + (tid >> 7);
    int ch = tid & 127;
    if (node >= N) return;
    int beg = offs[node], end = offs[node + 1];
    float a0 = 0.0f, a1 = 0.0f;
    int i = beg;
    for (; i + 1 < end; i += 2) {
        int s0 = perm[i], s1 = perm[i + 1];
        a0 += feat[(long long)s0 * 128 + ch];
        a1 += feat[(long long)s1 * 128 + ch];
    }
    if (i < end) a0 += feat[(long long)perm[i] * 128 + ch];
    float deg = (float)(end - beg);
    float mean = (a0 + a1) / fmaxf(deg, 1.0f);
    short2 c = cvt_split(mean);
    mhi[(long long)node * 128 + ch] = c.x;
    mlo[(long long)node * 128 + ch] = c.y;
}

// ---------------- layer-2 agg fused epilogue: out = mean(g) + r2 + b2l ----------------
__global__ __launch_bounds__(256) void aggout_k(const float* __restrict__ g,
                                                const int* __restrict__ perm,
                                                const int* __restrict__ offs,
                                                const float* __restrict__ r2,
                                                const float* __restrict__ b2l,
                                                float* __restrict__ out, int N) {
    int tid = threadIdx.x;
    int node = blockIdx.x * 2 + (tid >> 7);
    int ch = tid & 127;
    if (node >= N) return;
    int beg = offs[node], end = offs[node + 1];
    float a0 = 0.0f, a1 = 0.0f;
    int i = beg;
    for (; i + 1 < end; i += 2) {
        int s0 = perm[i], s1 = perm[i + 1];
        a0 += g[(long long)s0 * 128 + ch];
        a1 += g[(long long)s1 * 128 + ch];
    }
    if (i < end) a0 += g[(long long)perm[i] * 128 + ch];
    float deg = (float)(end - beg);
    float mean = (a0 + a1) / fmaxf(deg, 1.0f);
    out[(long long)node * 128 + ch] = mean + r2[(long long)node * 128 + ch] + b2l[ch];
}

// ---------------- async global->LDS, 16B/lane ----------------
__device__ inline void gload16(const void* g, void* l) {
    __builtin_amdgcn_global_load_lds(
        (const __attribute__((address_space(1))) unsigned int*)g,
        (__attribute__((address_space(3))) unsigned int*)l,
        16, 0, 0);
}

// ================= split-bf16 MFMA GEMM, occupancy-first =================
// C ~= Alo.Bhi + Ahi.Blo + Ahi.Bhi. Tile 128x128, 4 waves (2x2), 4x4 frags.
// K=256 in 8 stages of BK=32, single-buffered. LDS rows are 128B holding
// [hi c0..3 | lo c0..3] interleaved; chunk c of row r lives at slot c^(r&7)
// (round-8-verified 0-conflict family). LDS total = 32 KiB -> 4 blocks/CU
// (16 waves/CU, 50% occupancy) with __launch_bounds__(256,4).
// MFMA operands SWAPPED: mfma(B_frag, A_frag) => D = C^T, so each lane holds
// 4 CONSECUTIVE output cols of one row -> 8B/16B coalesced epilogue stores.
template <int LAYER>
__global__ __launch_bounds__(256, 4) void gemm_mfma_k(
        const short* __restrict__ A0hi, const short* __restrict__ A0lo,
        const short* __restrict__ A1hi, const short* __restrict__ A1lo,
        const short* __restrict__ B0hi, const short* __restrict__ B0lo,
        const short* __restrict__ B1hi, const short* __restrict__ B1lo,
        const float* __restrict__ bias,
        float* __restrict__ O0, float* __restrict__ O1,
        short* __restrict__ OHi, short* __restrict__ OLo, int N) {
    constexpr int AS_ = (LAYER == 1) ? 128 : 256;   // A row stride (shorts)
    constexpr int BS_ = (LAYER == 1) ? 128 : 256;   // B row stride (shorts)
    __shared__ short As[128 * 64];   // row = 64 shorts = 128B, hi|lo interleaved
    __shared__ short Bs[128 * 64];

    const int bid = blockIdx.x;
    const int m0 = (bid >> 1) * 128;
    const int n0 = (bid & 1) * 128;
    const int tid = threadIdx.x;
    const int lane = tid & 63;
    const int wid = tid >> 6;
    const int wm = wid >> 1, wn = wid & 1;
    const int lr = lane & 15, lg = lane >> 4;

    // B K-half sources
    const short *bh0, *bl0, *bh1, *bl1;
    if constexpr (LAYER == 1) {
        bh0 = B0hi + (long long)n0 * 128;   // W1l rows n0.. (k 0..127)
        bl0 = B0lo + (long long)n0 * 128;
        bh1 = B1hi + (long long)n0 * 128;   // W1r rows n0.. (k 128..255)
        bl1 = B1lo + (long long)n0 * 128;
    } else {
        const short* wh = (n0 == 0) ? B0hi : B1hi;
        const short* wl = (n0 == 0) ? B0lo : B1lo;
        bh0 = wh;       bl0 = wl;           // k 0..127
        bh1 = wh + 128; bl1 = wl + 128;     // k 128..255
    }

    // DMA lane geometry: per issue 8 rows x 8 slots (1KB linear LDS)
    const int rq = lane >> 3;          // row within segment
    const int sl = lane & 7;           // LDS slot this lane fills

    f32x4 acc[4][4];
#pragma unroll
    for (int i = 0; i < 4; i++)
#pragma unroll
        for (int j = 0; j < 4; j++) acc[i][j] = (f32x4)0.0f;

    auto STAGE = [&](int kt) {
        const short* Ah = (kt < 4) ? A0hi : A1hi;
        const short* Al = (kt < 4) ? A0lo : A1lo;
        const short* Bh = (kt < 4) ? bh0 : bh1;
        const short* Bl = (kt < 4) ? bl0 : bl1;
        const int koff = (kt & 3) * 32;
#pragma unroll
        for (int it = 0; it < 4; ++it) {
            int seg = wid * 4 + it;          // 0..15 (8 rows each)
            int row = seg * 8 + rq;          // 0..127
            int c = sl ^ (row & 7);          // global chunk for this slot
            // A
            {
                int gn = m0 + row;
                const short* srcA = (c < 4)
                    ? (Ah + (long long)gn * AS_ + koff + c * 8)
                    : (Al + (long long)gn * AS_ + koff + (c - 4) * 8);
                if (gn < N) gload16(srcA, &As[seg * 512]);
            }
            // B (rows always valid)
            {
                const short* srcB = (c < 4)
                    ? (Bh + (long long)row * BS_ + koff + c * 8)
                    : (Bl + (long long)row * BS_ + koff + (c - 4) * 8);
                gload16(srcB, &Bs[seg * 512]);
            }
        }
    };

    auto COMPUTE = [&]() {
        bf16x8 bh[4], bl[4];
#pragma unroll
        for (int fc = 0; fc < 4; ++fc) {
            int c_ = wn * 64 + fc * 16 + lr;
            bh[fc] = *(const bf16x8*)&Bs[c_ * 64 + ((lg    ) ^ (c_ & 7)) * 8];
            bl[fc] = *(const bf16x8*)&Bs[c_ * 64 + ((lg + 4) ^ (c_ & 7)) * 8];
        }
#pragma unroll
        for (int fr = 0; fr < 4; ++fr) {
            int r_ = wm * 64 + fr * 16 + lr;
            bf16x8 ah = *(const bf16x8*)&As[r_ * 64 + ((lg    ) ^ (r_ & 7)) * 8];
            bf16x8 al = *(const bf16x8*)&As[r_ * 64 + ((lg + 4) ^ (r_ & 7)) * 8];
#pragma unroll
            for (int fc = 0; fc < 4; ++fc) {
                acc[fr][fc] = __builtin_amdgcn_mfma_f32_16x16x32_bf16(bh[fc], al, acc[fr][fc], 0, 0, 0);
                acc[fr][fc] = __builtin_amdgcn_mfma_f32_16x16x32_bf16(bl[fc], ah, acc[fr][fc], 0, 0, 0);
                acc[fr][fc] = __builtin_amdgcn_mfma_f32_16x16x32_bf16(bh[fc], ah, acc[fr][fc], 0, 0, 0);
            }
        }
    };

#pragma unroll
    for (int kt = 0; kt < 8; ++kt) {
        __syncthreads();      // readers of prev stage done
        STAGE(kt);
        __syncthreads();      // drain DMA + barrier: stage kt ready
        COMPUTE();
    }

    // ---- epilogue (transposed D): lane holds row r = ...+lr,
    //      cols cb..cb+3 with cb = base + fc*16 + lg*4 ----
    if constexpr (LAYER == 1) {
#pragma unroll
        for (int fr = 0; fr < 4; ++fr) {
            int r = m0 + wm * 64 + fr * 16 + lr;
            if (r >= N) continue;
#pragma unroll
            for (int fc = 0; fc < 4; ++fc) {
                int cb = n0 + wn * 64 + fc * 16 + lg * 4;
                float4 bv = *(const float4*)&bias[cb];
                float x0 = fmaxf(acc[fr][fc][0] + bv.x, 0.0f);
                float x1 = fmaxf(acc[fr][fc][1] + bv.y, 0.0f);
                float x2 = fmaxf(acc[fr][fc][2] + bv.z, 0.0f);
                float x3 = fmaxf(acc[fr][fc][3] + bv.w, 0.0f);
                short2 t0 = cvt_split(x0), t1 = cvt_split(x1);
                short2 t2 = cvt_split(x2), t3 = cvt_split(x3);
                short4 hv = make_short4(t0.x, t1.x, t2.x, t3.x);
                short4 lv = make_short4(t0.y, t1.y, t2.y, t3.y);
                *(short4*)&OHi[(long long)r * 256 + cb] = hv;
                *(short4*)&OLo[(long long)r * 256 + cb] = lv;
            }
        }
    } else {
        float* dp = (n0 == 0) ? O0 : O1;
#pragma unroll
        for (int fr = 0; fr < 4; ++fr) {
            int r = m0 + wm * 64 + fr * 16 + lr;
            if (r >= N) continue;
#pragma unroll
            for (int fc = 0; fc < 4; ++fc) {
                int cb = wn * 64 + fc * 16 + lg * 4;   // 0..127 within dp
                *(f32x4*)&dp[(long long)r * 128 + cb] = acc[fr][fc];
            }
        }
    }
}

extern "C" void kernel_launch(void* const* d_in, const int* in_sizes, int n_in,
                              void* d_out, int out_size, void* d_ws, size_t ws_size,
                              hipStream_t stream) {
    const float* x   = (const float*)d_in[0];
    const int*   ei  = (const int*)d_in[1];     // [2, E]
    const float* W1l = (const float*)d_in[2];
    const float* b1l = (const float*)d_in[3];
    const float* W1r = (const float*)d_in[4];
    const float* W2l = (const float*)d_in[5];
    const float* b2l = (const float*)d_in[6];
    const float* W2r = (const float*)d_in[7];
    float* out = (float*)d_out;

    const int N = N_NODES, E = N_EDGES;
    const int* srcI = ei;
    const int* dstI = ei + E;

    char* ws = (char*)d_ws;
    size_t off = 0;
    auto alloc = [&](size_t bytes) {
        size_t o = off;
        off += (bytes + 511) & ~(size_t)511;
        return o;
    };
    size_t off_cnt   = alloc((size_t)N * 4);
    size_t off_offs  = alloc((size_t)(N + 1) * 4);
    size_t off_cur   = alloc((size_t)N * 4);
    size_t off_bsum  = alloc((size_t)SCAN_NB * 4);
    size_t off_boff  = alloc((size_t)SCAN_NB * 4);
    size_t off_perm  = alloc((size_t)E * 4);
    size_t off_x2    = alloc((size_t)N * 128 * 4);     // xhi | xlo
    size_t off_m2    = alloc((size_t)N * 128 * 4);     // mhi | mlo; reused as g (fp32)
    size_t off_h2    = alloc((size_t)N * 256 * 4);     // hhi | hlo
    size_t off_r2    = alloc((size_t)N * 128 * 4);     // fp32
    size_t off_w     = alloc((size_t)8 * 256 * 128 * 2); // 4 weights x hi/lo
    int*   cntI  = (int*)(ws + off_cnt);
    int*   offs  = (int*)(ws + off_offs);
    int*   cur   = (int*)(ws + off_cur);
    int*   bsum  = (int*)(ws + off_bsum);
    int*   boff  = (int*)(ws + off_boff);
    int*   perm  = (int*)(ws + off_perm);
    short* xhi   = (short*)(ws + off_x2);
    short* xlo   = xhi + (size_t)N * 128;
    short* mhi   = (short*)(ws + off_m2);
    short* mlo   = mhi + (size_t)N * 128;
    float* g     = (float*)(ws + off_m2);              // aliases mean (dead after gemm1)
    short* hhi   = (short*)(ws + off_h2);
    short* hlo   = hhi + (size_t)N * 256;
    float* r2    = (float*)(ws + off_r2);
    short* wbuf  = (short*)(ws + off_w);
    const int WSZ = 256 * 128;
    short* w1lhi = wbuf;            short* w1llo = wbuf + WSZ;
    short* w1rhi = wbuf + 2 * WSZ;  short* w1rlo = wbuf + 3 * WSZ;
    short* w2lhi = wbuf + 4 * WSZ;  short* w2llo = wbuf + 5 * WSZ;
    short* w2rhi = wbuf + 6 * WSZ;  short* w2rlo = wbuf + 7 * WSZ;

    // ---- CSR build ----
    (void)hipMemsetAsync(cntI, 0, (size_t)N * 4, stream);
    count_int_k<<<(E + 255) / 256, 256, 0, stream>>>(dstI, cntI, E);
    scan1_k<<<SCAN_NB, 256, 0, stream>>>(cntI, offs, bsum, N);
    scan2_k<<<1, 256, 0, stream>>>(bsum, boff, SCAN_NB);
    scan3_k<<<(N + 255) / 256, 256, 0, stream>>>(offs, cur, boff, N, E);
    fill_k<<<(E + 255) / 256, 256, 0, stream>>>(srcI, dstI, cur, perm, E);

    // ---- pre-split conversions ----
    {
        int n8x = N * 16;                          // N*128/8
        cvt_pair_k<<<(n8x + 255) / 256, 256, 0, stream>>>(x, xhi, xlo, n8x);
        int n8w = WSZ / 8;                         // 4096
        cvt_pair_k<<<(n8w + 255) / 256, 256, 0, stream>>>(W1l, w1lhi, w1llo, n8w);
        cvt_pair_k<<<(n8w + 255) / 256, 256, 0, stream>>>(W1r, w1rhi, w1rlo, n8w);
        cvt_pair_k<<<(n8w + 255) / 256, 256, 0, stream>>>(W2l, w2lhi, w2llo, n8w);
        cvt_pair_k<<<(n8w + 255) / 256, 256, 0, stream>>>(W2r, w2rhi, w2rlo, n8w);
    }

    // ---- layer 1 ----
    aggmean_k<<<(N + 1) / 2, 256, 0, stream>>>(x, perm, offs, mhi, mlo, N);
    {
        int nblk = ((N + 127) / 128) * 2;
        gemm_mfma_k<1><<<nblk, 256, 0, stream>>>(mhi, mlo, xhi, xlo,
                                                 w1lhi, w1llo, w1rhi, w1rlo,
                                                 b1l, nullptr, nullptr, hhi, hlo, N);
    }

    // ---- layer 2 ----
    {
        int nblk = ((N + 127) / 128) * 2;
        gemm_mfma_k<2><<<nblk, 256, 0, stream>>>(hhi, hlo, hhi + 128, hlo + 128,
                                                 w2lhi, w2llo, w2rhi, w2rlo,
                                                 nullptr, g, r2, nullptr, nullptr, N);
    }
    aggout_k<<<(N + 1) / 2, 256, 0, stream>>>(g, perm, offs, r2, b2l, out, N);
}

// Round 11
// 417.897 us; speedup vs baseline: 1.5788x; 1.5788x over previous
//
#include <hip/hip_runtime.h>

#define N_NODES 100000
#define N_EDGES 800000
// IN=128, HID=256, OUT=128
#define SCAN_CHUNK 1024
#define SCAN_NB ((N_NODES + SCAN_CHUNK - 1) / SCAN_CHUNK)   // 98

typedef __attribute__((ext_vector_type(8))) short bf16x8;
typedef __attribute__((ext_vector_type(4))) float f32x4;

// ---------------- degree count (int atomics) ----------------
__global__ void count_int_k(const int* __restrict__ dst, int* __restrict__ cnt, int E) {
    int i = blockIdx.x * blockDim.x + threadIdx.x;
    if (i < E) atomicAdd(&cnt[dst[i]], 1);
}

// ---------------- scan pass 1 ----------------
__global__ __launch_bounds__(256) void scan1_k(const int* __restrict__ cnt,
                                               int* __restrict__ offs,
                                               int* __restrict__ bsums, int N) {
    __shared__ int s[256];
    int t = threadIdx.x;
    int base = blockIdx.x * SCAN_CHUNK + t * 4;
    int v0 = (base + 0 < N) ? cnt[base + 0] : 0;
    int v1 = (base + 1 < N) ? cnt[base + 1] : 0;
    int v2 = (base + 2 < N) ? cnt[base + 2] : 0;
    int v3 = (base + 3 < N) ? cnt[base + 3] : 0;
    int tsum = v0 + v1 + v2 + v3;
    s[t] = tsum;
    __syncthreads();
    for (int off = 1; off < 256; off <<= 1) {
        int val = (t >= off) ? s[t - off] : 0;
        __syncthreads();
        s[t] += val;
        __syncthreads();
    }
    int excl = s[t] - tsum;
    if (base + 0 < N) offs[base + 0] = excl;
    if (base + 1 < N) offs[base + 1] = excl + v0;
    if (base + 2 < N) offs[base + 2] = excl + v0 + v1;
    if (base + 3 < N) offs[base + 3] = excl + v0 + v1 + v2;
    if (t == 255) bsums[blockIdx.x] = s[255];
}

// ---------------- scan pass 2 ----------------
__global__ __launch_bounds__(256) void scan2_k(const int* __restrict__ bsums,
                                               int* __restrict__ boffs, int nb) {
    __shared__ int s[256];
    int t = threadIdx.x;
    int v = (t < nb) ? bsums[t] : 0;
    s[t] = v;
    __syncthreads();
    for (int off = 1; off < 256; off <<= 1) {
        int val = (t >= off) ? s[t - off] : 0;
        __syncthreads();
        s[t] += val;
        __syncthreads();
    }
    if (t < nb) boffs[t] = s[t] - v;
}

// ---------------- scan pass 3 ----------------
__global__ void scan3_k(int* __restrict__ offs, int* __restrict__ cursor,
                        const int* __restrict__ boffs, int N, int E) {
    int i = blockIdx.x * blockDim.x + threadIdx.x;
    if (i < N) {
        int v = offs[i] + boffs[i >> 10];
        offs[i] = v;
        cursor[i] = v;
    }
    if (i == 0) offs[N] = E;
}

// ---------------- bucket fill ----------------
__global__ void fill_k(const int* __restrict__ src, const int* __restrict__ dst,
                       int* __restrict__ cursor, int* __restrict__ perm, int E) {
    int e = blockIdx.x * blockDim.x + threadIdx.x;
    if (e < E) {
        int d = dst[e];
        int slot = atomicAdd(&cursor[d], 1);
        perm[slot] = src[e];
    }
}

// ---------------- split fp32 -> (bf16 hi, bf16 lo) ----------------
__device__ inline short2 cvt_split(float a) {
    unsigned u = __builtin_bit_cast(unsigned, a);
    unsigned r = u + 0x7FFF + ((u >> 16) & 1);
    unsigned short h = (unsigned short)(r >> 16);
    float hf = __builtin_bit_cast(float, (unsigned)h << 16);
    float l = a - hf;
    unsigned ul = __builtin_bit_cast(unsigned, l);
    unsigned rl = ul + 0x7FFF + ((ul >> 16) & 1);
    return make_short2((short)h, (short)(rl >> 16));
}

// ---------------- bulk pair-conversion (8 floats/thread) ----------------
__global__ __launch_bounds__(256) void cvt_pair_k(const float* __restrict__ in,
                                                  short* __restrict__ hi,
                                                  short* __restrict__ lo, int n8) {
    int i = blockIdx.x * blockDim.x + threadIdx.x;
    if (i >= n8) return;
    const float4* p = (const float4*)in + (long long)i * 2;
    float4 v0 = p[0], v1 = p[1];
    bf16x8 hv, lv;
    short2 c;
    c = cvt_split(v0.x); hv[0] = c.x; lv[0] = c.y;
    c = cvt_split(v0.y); hv[1] = c.x; lv[1] = c.y;
    c = cvt_split(v0.z); hv[2] = c.x; lv[2] = c.y;
    c = cvt_split(v0.w); hv[3] = c.x; lv[3] = c.y;
    c = cvt_split(v1.x); hv[4] = c.x; lv[4] = c.y;
    c = cvt_split(v1.y); hv[5] = c.x; lv[5] = c.y;
    c = cvt_split(v1.z); hv[6] = c.x; lv[6] = c.y;
    c = cvt_split(v1.w); hv[7] = c.x; lv[7] = c.y;
    *(bf16x8*)&hi[(long long)i * 8] = hv;
    *(bf16x8*)&lo[(long long)i * 8] = lv;
}

// ---------------- gather-mean (float4/thread) -> bf16 hi/lo ----------------
__global__ __launch_bounds__(256) void aggmean_k(const float* __restrict__ feat,
                                                 const int* __restrict__ perm,
                                                 const int* __restrict__ offs,
                                                 short* __restrict__ mhi,
                                                 short* __restrict__ mlo, int N) {
    int tid = threadIdx.x;
    int node = blockIdx.x * 8 + (tid >> 5);
    int q = tid & 31;                       // float4 lane: channels q*4..q*4+3
    if (node >= N) return;
    int beg = offs[node], end = offs[node + 1];
    float ax = 0, ay = 0, az = 0, aw = 0;
    float bx = 0, by = 0, bz = 0, bw = 0;
    int i = beg;
    for (; i + 1 < end; i += 2) {
        float4 v0 = ((const float4*)feat)[(long long)perm[i] * 32 + q];
        float4 v1 = ((const float4*)feat)[(long long)perm[i + 1] * 32 + q];
        ax += v0.x; ay += v0.y; az += v0.z; aw += v0.w;
        bx += v1.x; by += v1.y; bz += v1.z; bw += v1.w;
    }
    if (i < end) {
        float4 v0 = ((const float4*)feat)[(long long)perm[i] * 32 + q];
        ax += v0.x; ay += v0.y; az += v0.z; aw += v0.w;
    }
    float rc = 1.0f / fmaxf((float)(end - beg), 1.0f);
    short2 c0 = cvt_split((ax + bx) * rc);
    short2 c1 = cvt_split((ay + by) * rc);
    short2 c2 = cvt_split((az + bz) * rc);
    short2 c3 = cvt_split((aw + bw) * rc);
    *(short4*)&mhi[(long long)node * 128 + q * 4] = make_short4(c0.x, c1.x, c2.x, c3.x);
    *(short4*)&mlo[(long long)node * 128 + q * 4] = make_short4(c0.y, c1.y, c2.y, c3.y);
}

// ---------------- layer-2 agg fused epilogue: out = mean(g) + r2 + b2l ----------------
__global__ __launch_bounds__(256) void aggout_k(const float* __restrict__ g,
                                                const int* __restrict__ perm,
                                                const int* __restrict__ offs,
                                                const float* __restrict__ r2,
                                                const float* __restrict__ b2l,
                                                float* __restrict__ out, int N) {
    int tid = threadIdx.x;
    int node = blockIdx.x * 8 + (tid >> 5);
    int q = tid & 31;
    if (node >= N) return;
    int beg = offs[node], end = offs[node + 1];
    float ax = 0, ay = 0, az = 0, aw = 0;
    float bx = 0, by = 0, bz = 0, bw = 0;
    int i = beg;
    for (; i + 1 < end; i += 2) {
        float4 v0 = ((const float4*)g)[(long long)perm[i] * 32 + q];
        float4 v1 = ((const float4*)g)[(long long)perm[i + 1] * 32 + q];
        ax += v0.x; ay += v0.y; az += v0.z; aw += v0.w;
        bx += v1.x; by += v1.y; bz += v1.z; bw += v1.w;
    }
    if (i < end) {
        float4 v0 = ((const float4*)g)[(long long)perm[i] * 32 + q];
        ax += v0.x; ay += v0.y; az += v0.z; aw += v0.w;
    }
    float rc = 1.0f / fmaxf((float)(end - beg), 1.0f);
    float4 rv = ((const float4*)r2)[(long long)node * 32 + q];
    float4 bv = ((const float4*)b2l)[q];
    float4 o;
    o.x = (ax + bx) * rc + rv.x + bv.x;
    o.y = (ay + by) * rc + rv.y + bv.y;
    o.z = (az + bz) * rc + rv.z + bv.z;
    o.w = (aw + bw) * rc + rv.w + bv.w;
    ((float4*)out)[(long long)node * 32 + q] = o;
}

// ---------------- async global->LDS, 16B/lane ----------------
__device__ inline void gload16(const void* g, void* l) {
    __builtin_amdgcn_global_load_lds(
        (const __attribute__((address_space(1))) unsigned int*)g,
        (__attribute__((address_space(3))) unsigned int*)l,
        16, 0, 0);
}

// ================= split-bf16 MFMA GEMM, 128x256 tile, 8 waves =================
// C ~= Ahi.Bhi + Ahi.Blo + Alo.Bhi. One block covers the FULL 256-col output:
// blocks = M/128 (782), 8 waves (2 row-halves x 4 col-quarters), 4x4 frags each.
// K=256 in 4 stages of BK=64, single-buffered drain (round-7 scheme: FETCH
// ideal, 0 conflicts). LDS = (128+256)*64*2*2B = 96 KiB -> 1 block/CU.
// Swizzle: chunk ch (8 shorts) of row r lives at slot ch^(r&7); DMA pre-swizzles
// the per-lane global source chunk (k8s = (lane&7)^(lane>>3)).
template <int LAYER>
__global__ __launch_bounds__(512, 2) void gemm_mfma_k(
        const short* __restrict__ A0hi, const short* __restrict__ A0lo,
        const short* __restrict__ A1hi, const short* __restrict__ A1lo,
        const short* __restrict__ B0hi, const short* __restrict__ B0lo,
        const short* __restrict__ B1hi, const short* __restrict__ B1lo,
        const float* __restrict__ bias,
        float* __restrict__ O0, float* __restrict__ O1,
        short* __restrict__ OHi, short* __restrict__ OLo, int N) {
    constexpr int AS_ = (LAYER == 1) ? 128 : 256;   // A row stride (shorts)
    __shared__ short AsHi[128 * 64];
    __shared__ short AsLo[128 * 64];
    __shared__ short BsHi[256 * 64];
    __shared__ short BsLo[256 * 64];

    const int m0 = blockIdx.x * 128;
    const int tid = threadIdx.x;
    const int lane = tid & 63;
    const int wid = tid >> 6;           // 0..7
    const int wm = wid >> 2, wn = wid & 3;
    const int lr = lane & 15, lg = lane >> 4;

    // DMA lane geometry: 8 rows x 8 slots x 16B = 1KB per issue
    const int r8 = lane >> 3;
    const int scs = lane & 7;
    const int k8s = scs ^ r8;           // pre-swizzled global source chunk

    f32x4 acc[4][4];
#pragma unroll
    for (int i = 0; i < 4; i++)
#pragma unroll
        for (int j = 0; j < 4; j++) acc[i][j] = (f32x4)0.0f;

#pragma unroll
    for (int kt = 0; kt < 4; ++kt) {
        __syncthreads();    // previous stage's readers done
        // ---- STAGE kt ----
        {
            const short* Ah = (kt < 2) ? A0hi : A1hi;
            const short* Al = (kt < 2) ? A0lo : A1lo;
            const int koff = (kt & 1) * 64;
            // A: 16 segments, 2 per wave
#pragma unroll
            for (int it = 0; it < 2; ++it) {
                int seg = wid * 2 + it;          // 0..15
                int row = seg * 8 + r8;          // 0..127
                int gn = m0 + row;
                long long aoff = (long long)gn * AS_ + koff + k8s * 8;
                if (gn < N) {
                    gload16(Ah + aoff, &AsHi[seg * 512]);
                    gload16(Al + aoff, &AsLo[seg * 512]);
                }
            }
            // B: 32 segments, 4 per wave (rows = output cols 0..255)
#pragma unroll
            for (int it = 0; it < 4; ++it) {
                int seg = wid * 4 + it;          // 0..31
                int row = seg * 8 + r8;          // 0..255
                const short *Bh, *Bl;
                long long boff;
                if constexpr (LAYER == 1) {
                    Bh = (kt < 2) ? B0hi : B1hi;    // W1l (k 0..127) / W1r (k 128..255)
                    Bl = (kt < 2) ? B0lo : B1lo;
                    boff = (long long)row * 128 + koff + k8s * 8;
                } else {
                    Bh = (row < 128) ? B0hi : B1hi; // W2l (cols 0..127) / W2r (128..255)
                    Bl = (row < 128) ? B0lo : B1lo;
                    boff = (long long)(row & 127) * 256 + kt * 64 + k8s * 8;
                }
                gload16(Bh + boff, &BsHi[seg * 512]);
                gload16(Bl + boff, &BsLo[seg * 512]);
            }
        }
        __syncthreads();    // drain DMA: stage kt ready
        // ---- COMPUTE kt: 2 k-steps of 32 ----
#pragma unroll
        for (int ks = 0; ks < 2; ++ks) {
            bf16x8 bh[4], bl[4];
#pragma unroll
            for (int fc = 0; fc < 4; ++fc) {
                int c_ = wn * 64 + fc * 16 + lr;
                int sc = (ks * 4 + lg) ^ (c_ & 7);
                bh[fc] = *(const bf16x8*)&BsHi[c_ * 64 + sc * 8];
                bl[fc] = *(const bf16x8*)&BsLo[c_ * 64 + sc * 8];
            }
#pragma unroll
            for (int fr = 0; fr < 4; ++fr) {
                int r_ = wm * 64 + fr * 16 + lr;
                int sc = (ks * 4 + lg) ^ (r_ & 7);
                bf16x8 ah = *(const bf16x8*)&AsHi[r_ * 64 + sc * 8];
                bf16x8 al = *(const bf16x8*)&AsLo[r_ * 64 + sc * 8];
#pragma unroll
                for (int fc = 0; fc < 4; ++fc) {
                    acc[fr][fc] = __builtin_amdgcn_mfma_f32_16x16x32_bf16(al, bh[fc], acc[fr][fc], 0, 0, 0);
                    acc[fr][fc] = __builtin_amdgcn_mfma_f32_16x16x32_bf16(ah, bl[fc], acc[fr][fc], 0, 0, 0);
                    acc[fr][fc] = __builtin_amdgcn_mfma_f32_16x16x32_bf16(ah, bh[fc], acc[fr][fc], 0, 0, 0);
                }
            }
        }
    }

    // ---- epilogue: C/D map col=lane&15, row=(lane>>4)*4+reg ----
    if constexpr (LAYER == 1) {
#pragma unroll
        for (int fc = 0; fc < 4; ++fc) {
            int col = wn * 64 + fc * 16 + lr;       // 0..255
            float bv = bias[col];
#pragma unroll
            for (int fr = 0; fr < 4; ++fr) {
#pragma unroll
                for (int j = 0; j < 4; ++j) {
                    int row = m0 + wm * 64 + fr * 16 + lg * 4 + j;
                    if (row < N) {
                        float val = fmaxf(acc[fr][fc][j] + bv, 0.0f);
                        short2 cc = cvt_split(val);
                        OHi[(long long)row * 256 + col] = cc.x;
                        OLo[(long long)row * 256 + col] = cc.y;
                    }
                }
            }
        }
    } else {
#pragma unroll
        for (int fc = 0; fc < 4; ++fc) {
            int col = wn * 64 + fc * 16 + lr;       // 0..255
            float* dp = (col < 128) ? O0 : O1;      // uniform per wn
            int dcol = col & 127;
#pragma unroll
            for (int fr = 0; fr < 4; ++fr) {
#pragma unroll
                for (int j = 0; j < 4; ++j) {
                    int row = m0 + wm * 64 + fr * 16 + lg * 4 + j;
                    if (row < N)
                        dp[(long long)row * 128 + dcol] = acc[fr][fc][j];
                }
            }
        }
    }
}

extern "C" void kernel_launch(void* const* d_in, const int* in_sizes, int n_in,
                              void* d_out, int out_size, void* d_ws, size_t ws_size,
                              hipStream_t stream) {
    const float* x   = (const float*)d_in[0];
    const int*   ei  = (const int*)d_in[1];     // [2, E]
    const float* W1l = (const float*)d_in[2];
    const float* b1l = (const float*)d_in[3];
    const float* W1r = (const float*)d_in[4];
    const float* W2l = (const float*)d_in[5];
    const float* b2l = (const float*)d_in[6];
    const float* W2r = (const float*)d_in[7];
    float* out = (float*)d_out;

    const int N = N_NODES, E = N_EDGES;
    const int* srcI = ei;
    const int* dstI = ei + E;

    char* ws = (char*)d_ws;
    size_t off = 0;
    auto alloc = [&](size_t bytes) {
        size_t o = off;
        off += (bytes + 511) & ~(size_t)511;
        return o;
    };
    size_t off_cnt   = alloc((size_t)N * 4);
    size_t off_offs  = alloc((size_t)(N + 1) * 4);
    size_t off_cur   = alloc((size_t)N * 4);
    size_t off_bsum  = alloc((size_t)SCAN_NB * 4);
    size_t off_boff  = alloc((size_t)SCAN_NB * 4);
    size_t off_perm  = alloc((size_t)E * 4);
    size_t off_x2    = alloc((size_t)N * 128 * 4);     // xhi | xlo
    size_t off_m2    = alloc((size_t)N * 128 * 4);     // mhi | mlo; reused as g (fp32)
    size_t off_h2    = alloc((size_t)N * 256 * 4);     // hhi | hlo
    size_t off_r2    = alloc((size_t)N * 128 * 4);     // fp32
    size_t off_w     = alloc((size_t)8 * 256 * 128 * 2); // 4 weights x hi/lo
    int*   cntI  = (int*)(ws + off_cnt);
    int*   offs  = (int*)(ws + off_offs);
    int*   cur   = (int*)(ws + off_cur);
    int*   bsum  = (int*)(ws + off_bsum);
    int*   boff  = (int*)(ws + off_boff);
    int*   perm  = (int*)(ws + off_perm);
    short* xhi   = (short*)(ws + off_x2);
    short* xlo   = xhi + (size_t)N * 128;
    short* mhi   = (short*)(ws + off_m2);
    short* mlo   = mhi + (size_t)N * 128;
    float* g     = (float*)(ws + off_m2);              // aliases mean (dead after gemm1)
    short* hhi   = (short*)(ws + off_h2);
    short* hlo   = hhi + (size_t)N * 256;
    float* r2    = (float*)(ws + off_r2);
    short* wbuf  = (short*)(ws + off_w);
    const int WSZ = 256 * 128;
    short* w1lhi = wbuf;            short* w1llo = wbuf + WSZ;
    short* w1rhi = wbuf + 2 * WSZ;  short* w1rlo = wbuf + 3 * WSZ;
    short* w2lhi = wbuf + 4 * WSZ;  short* w2llo = wbuf + 5 * WSZ;
    short* w2rhi = wbuf + 6 * WSZ;  short* w2rlo = wbuf + 7 * WSZ;

    // ---- CSR build ----
    (void)hipMemsetAsync(cntI, 0, (size_t)N * 4, stream);
    count_int_k<<<(E + 255) / 256, 256, 0, stream>>>(dstI, cntI, E);
    scan1_k<<<SCAN_NB, 256, 0, stream>>>(cntI, offs, bsum, N);
    scan2_k<<<1, 256, 0, stream>>>(bsum, boff, SCAN_NB);
    scan3_k<<<(N + 255) / 256, 256, 0, stream>>>(offs, cur, boff, N, E);
    fill_k<<<(E + 255) / 256, 256, 0, stream>>>(srcI, dstI, cur, perm, E);

    // ---- pre-split conversions ----
    {
        int n8x = N * 16;                          // N*128/8
        cvt_pair_k<<<(n8x + 255) / 256, 256, 0, stream>>>(x, xhi, xlo, n8x);
        int n8w = WSZ / 8;                         // 4096
        cvt_pair_k<<<(n8w + 255) / 256, 256, 0, stream>>>(W1l, w1lhi, w1llo, n8w);
        cvt_pair_k<<<(n8w + 255) / 256, 256, 0, stream>>>(W1r, w1rhi, w1rlo, n8w);
        cvt_pair_k<<<(n8w + 255) / 256, 256, 0, stream>>>(W2l, w2lhi, w2llo, n8w);
        cvt_pair_k<<<(n8w + 255) / 256, 256, 0, stream>>>(W2r, w2rhi, w2rlo, n8w);
    }

    // ---- layer 1 ----
    aggmean_k<<<(N + 7) / 8, 256, 0, stream>>>(x, perm, offs, mhi, mlo, N);
    {
        int nblk = (N + 127) / 128;
        gemm_mfma_k<1><<<nblk, 512, 0, stream>>>(mhi, mlo, xhi, xlo,
                                                 w1lhi, w1llo, w1rhi, w1rlo,
                                                 b1l, nullptr, nullptr, hhi, hlo, N);
    }

    // ---- layer 2 ----
    {
        int nblk = (N + 127) / 128;
        gemm_mfma_k<2><<<nblk, 512, 0, stream>>>(hhi, hlo, hhi + 128, hlo + 128,
                                                 w2lhi, w2llo, w2rhi, w2rlo,
                                                 nullptr, g, r2, nullptr, nullptr, N);
    }
    aggout_k<<<(N + 7) / 8, 256, 0, stream>>>(g, perm, offs, r2, b2l, out, N);
}